// Round 5
// baseline (115.975 us; speedup 1.0000x reference)
//
#include <hip/hip_runtime.h>
#include <hip/hip_bf16.h>

typedef __bf16 bf16_t;
typedef __bf16 bf16x4 __attribute__((ext_vector_type(4)));
typedef __bf16 bf16x8 __attribute__((ext_vector_type(8)));
typedef float f32x4 __attribute__((ext_vector_type(4)));

constexpr int B = 4, T = 4096, C = 1024, H = 64;

__device__ __forceinline__ void gll16(const void* g, void* l) {
  __builtin_amdgcn_global_load_lds(
      (const __attribute__((address_space(1))) void*)g,
      (__attribute__((address_space(3))) void*)l, 16, 0, 0);
}

// ---------------------------------------------------------------------------
// Kernel 1: weights -> bf16, transposed WT[w][h][c], w in {q,k,v}.
// Wq folded with 0.125 * log2(e): softmax runs in exp2 domain.
// ---------------------------------------------------------------------------
__global__ __launch_bounds__(256) void wconv_kernel(
    const float* __restrict__ Wk, const float* __restrict__ Wq,
    const float* __restrict__ Wv, bf16_t* __restrict__ WT) {
  int idx = blockIdx.x * 256 + threadIdx.x;
  if (idx >= 3 * H * C) return;
  int w = idx / (H * C);
  int rem = idx - w * H * C;
  int h = rem / C;
  int c = rem - h * C;
  const float* src = (w == 0) ? Wq : (w == 1) ? Wk : Wv;
  float f = src[c * H + h];
  if (w == 0) f *= 0.125f * 1.44269504088896f;
  WT[idx] = (bf16_t)f;
}

// ---------------------------------------------------------------------------
// Kernel 2: fused QKV projection, LDS-staged 2-phase pipeline.
// BM=32 rows, BK=64, grid=512 (2 blocks/CU -> 8 waves/CU).
// 4 waves = 2 row-halves x 2 col-halves (6 nt each).
// XOR swizzle ((row&7)<<4) on global source + LDS read (rule 21).
// ---------------------------------------------------------------------------
__global__ __launch_bounds__(256, 2) void proj_kernel(
    const float* __restrict__ x, const bf16_t* __restrict__ WT,
    bf16_t* __restrict__ qb, bf16_t* __restrict__ kb, bf16_t* __restrict__ vT) {
  __shared__ __align__(16) char xsm[2][8192];   // 32 rows x 256B, swizzled
  __shared__ __align__(16) char wsm[2][24576];  // 192 rows x 128B, swizzled
  const int tid = threadIdx.x;
  const int lane = tid & 63;
  const int wave = tid >> 6;
  const int lr = lane & 15, lg = lane >> 4;
  const int rw = wave & 1, cw = wave >> 1;
  const int m0 = blockIdx.x * 32;

  f32x4 acc[6];
#pragma unroll
  for (int i = 0; i < 6; ++i) acc[i] = f32x4{0.f, 0.f, 0.f, 0.f};

  auto stage = [&](int buf, int ks) {
#pragma unroll
    for (int c = 0; c < 2; ++c) {  // x tile: 32 rows x 256B
      const int row = c * 16 + (tid >> 4);
      const int scb = ((tid & 15) * 16) ^ ((row & 7) << 4);
      gll16(x + (size_t)(m0 + row) * C + ks + (scb >> 2),
            &xsm[buf][c * 4096 + tid * 16]);
    }
#pragma unroll
    for (int c = 0; c < 6; ++c) {  // W tile: 192 rows x 128B
      const int row = c * 32 + (tid >> 3);
      const int scb = ((tid & 7) * 16) ^ ((row & 7) << 4);
      gll16(WT + (size_t)row * C + ks + (scb >> 1),
            &wsm[buf][c * 4096 + tid * 16]);
    }
  };

  stage(0, 0);
  __syncthreads();
  for (int t = 0; t < 16; ++t) {
    const int cur = t & 1;
    if (t < 15) stage(cur ^ 1, (t + 1) * 64);
    const char* xb_ = xsm[cur];
    const char* wb_ = wsm[cur];
#pragma unroll
    for (int ksub = 0; ksub < 2; ++ksub) {
      const int xrow = rw * 16 + lr;
      const int xsw = (xrow & 7) << 4;
      const int cb = ksub * 128 + lg * 32;
      const f32x4 xa = *(const f32x4*)(xb_ + xrow * 256 + (cb ^ xsw));
      const f32x4 xv = *(const f32x4*)(xb_ + xrow * 256 + ((cb + 16) ^ xsw));
      bf16x8 af;
      af[0] = (bf16_t)xa[0]; af[1] = (bf16_t)xa[1];
      af[2] = (bf16_t)xa[2]; af[3] = (bf16_t)xa[3];
      af[4] = (bf16_t)xv[0]; af[5] = (bf16_t)xv[1];
      af[6] = (bf16_t)xv[2]; af[7] = (bf16_t)xv[3];
#pragma unroll
      for (int t2 = 0; t2 < 6; ++t2) {
        const int nt = cw * 6 + t2;
        const int wrow = nt * 16 + lr;
        const bf16x8 wf = *(const bf16x8*)(
            wb_ + wrow * 128 + ((ksub * 64 + lg * 16) ^ ((wrow & 7) << 4)));
        acc[t2] = __builtin_amdgcn_mfma_f32_16x16x32_bf16(af, wf, acc[t2], 0, 0, 0);
      }
    }
    __syncthreads();
  }

#pragma unroll
  for (int t2 = 0; t2 < 6; ++t2) {
    const int nt = cw * 6 + t2;
    const int wsel = nt >> 2;
    const int h = (nt & 3) * 16 + lr;
#pragma unroll
    for (int r = 0; r < 4; ++r) {
      const int row = m0 + rw * 16 + lg * 4 + r;
      bf16_t val = (bf16_t)acc[t2][r];
      if (wsel == 0)
        qb[(size_t)row * H + h] = val;
      else if (wsel == 1)
        kb[(size_t)row * H + h] = val;
      else
        vT[((size_t)(row >> 12) * H + h) * T + (row & (T - 1))] = val;
    }
  }
}

// ---------------------------------------------------------------------------
// Kernel 3: causal flash attention, balanced pairs, swapped MFMAs,
// software-pipelined K prefetch (next chunk's K issued after current QK).
// ---------------------------------------------------------------------------
__global__ __launch_bounds__(512, 4) void flash_kernel(
    const bf16_t* __restrict__ qb, const bf16_t* __restrict__ kb,
    const bf16_t* __restrict__ vT, float* __restrict__ out) {
  __shared__ union {
    __align__(16) bf16_t p[8][16][72];  // P round-trip, per wave
    struct {
      __align__(16) float acc[8][64][20];  // [wave][lane][nt*4+r]
      float ml[8][16][2];                  // [wave][q-row][m,l]
    } red;
  } sm;

  const int lane = threadIdx.x & 63;
  const int wave = threadIdx.x >> 6;
  const int lr = lane & 15, lg = lane >> 4;
  const int j = blockIdx.x >> 2;
  const int b = blockIdx.x & 3;
  const bf16_t* Kb = kb + (size_t)b * T * H;
  const bf16_t* Vb = vT + (size_t)b * H * T;

  for (int phase = 0; phase < 2; ++phase) {
    const int qg = phase ? (127 - j) : (128 + j);
    const int q0 = qg * 16;
    const bf16_t* qp = qb + (size_t)(b * T + q0 + lr) * H;
    const bf16x8 qf0 = *(const bf16x8*)(qp + lg * 8);
    const bf16x8 qf1 = *(const bf16x8*)(qp + 32 + lg * 8);

    f32x4 acc[4];
#pragma unroll
    for (int t = 0; t < 4; ++t) acc[t] = f32x4{0.f, 0.f, 0.f, 0.f};
    float m = -1e30f, l = 0.f;

    int k0 = wave * 64;
    const int nk = q0 + 16;
    if (k0 < nk) {
      bf16x8 kf[4][2];
#pragma unroll
      for (int st = 0; st < 4; ++st) {
        const bf16_t* kp = Kb + (size_t)(k0 + st * 16 + lr) * H + lg * 8;
        kf[st][0] = *(const bf16x8*)(kp);
        kf[st][1] = *(const bf16x8*)(kp + 32);
      }
      while (true) {
        // V loads first: land during QK+softmax
        bf16x8 vf[4][2];
#pragma unroll
        for (int nt = 0; nt < 4; ++nt) {
          const bf16_t* vp = Vb + (size_t)(nt * 16 + lr) * T + k0 + lg * 8;
          vf[nt][0] = *(const bf16x8*)(vp);
          vf[nt][1] = *(const bf16x8*)(vp + 32);
        }
        const f32x4 z = f32x4{0.f, 0.f, 0.f, 0.f};
        f32x4 S[4];
#pragma unroll
        for (int st = 0; st < 4; ++st) {
          S[st] = __builtin_amdgcn_mfma_f32_16x16x32_bf16(kf[st][0], qf0, z, 0, 0, 0);
          S[st] = __builtin_amdgcn_mfma_f32_16x16x32_bf16(kf[st][1], qf1, S[st], 0, 0, 0);
        }
        // prefetch next chunk's K (kf dead after QK -> regs reused)
        const int k1 = k0 + 512;
        const bool more = (k1 < nk);
        bf16x8 kn[4][2];
        if (more) {
#pragma unroll
          for (int st = 0; st < 4; ++st) {
            const bf16_t* kp = Kb + (size_t)(k1 + st * 16 + lr) * H + lg * 8;
            kn[st][0] = *(const bf16x8*)(kp);
            kn[st][1] = *(const bf16x8*)(kp + 32);
          }
        }
        if (k0 + 63 > q0) {  // causal mask, diagonal chunks only
#pragma unroll
          for (int st = 0; st < 4; ++st)
#pragma unroll
            for (int r = 0; r < 4; ++r)
              S[st][r] = (k0 + st * 16 + lg * 4 + r > q0 + lr) ? -1e30f : S[st][r];
        }
        // per-lane softmax (exp2 domain; scale folded into Wq)
        float t01 = fmaxf(fmaxf(S[0][0], S[0][1]), fmaxf(S[0][2], S[0][3]));
        float t23 = fmaxf(fmaxf(S[1][0], S[1][1]), fmaxf(S[1][2], S[1][3]));
        float t45 = fmaxf(fmaxf(S[2][0], S[2][1]), fmaxf(S[2][2], S[2][3]));
        float t67 = fmaxf(fmaxf(S[3][0], S[3][1]), fmaxf(S[3][2], S[3][3]));
        float t = fmaxf(fmaxf(t01, t23), fmaxf(t45, t67));
        t = fmaxf(t, __shfl_xor(t, 16));
        t = fmaxf(t, __shfl_xor(t, 32));
        const float mn = fmaxf(m, t);
        const float alpha = __builtin_amdgcn_exp2f(m - mn);
        m = mn;
        float rs = 0.f;
#pragma unroll
        for (int st = 0; st < 4; ++st)
#pragma unroll
          for (int r = 0; r < 4; ++r) {
            S[st][r] = __builtin_amdgcn_exp2f(S[st][r] - mn);
            rs += S[st][r];
          }
        rs += __shfl_xor(rs, 16);
        rs += __shfl_xor(rs, 32);
        l = l * alpha + rs;
        // P -> LDS (packed b64) -> B-fragment
#pragma unroll
        for (int st = 0; st < 4; ++st) {
          bf16x4 pk;
          pk[0] = (bf16_t)S[st][0]; pk[1] = (bf16_t)S[st][1];
          pk[2] = (bf16_t)S[st][2]; pk[3] = (bf16_t)S[st][3];
          *(bf16x4*)(&sm.p[wave][lr][st * 16 + lg * 4]) = pk;
        }
        // rescale (per-lane scalar: acc col = q = lr) while LDS lands
#pragma unroll
        for (int nt = 0; nt < 4; ++nt)
#pragma unroll
          for (int r = 0; r < 4; ++r) acc[nt][r] *= alpha;
        const bf16x8 pf0 = *(const bf16x8*)(&sm.p[wave][lr][lg * 8]);
        const bf16x8 pf1 = *(const bf16x8*)(&sm.p[wave][lr][32 + lg * 8]);
#pragma unroll
        for (int nt = 0; nt < 4; ++nt) {
          acc[nt] = __builtin_amdgcn_mfma_f32_16x16x32_bf16(vf[nt][0], pf0, acc[nt], 0, 0, 0);
          acc[nt] = __builtin_amdgcn_mfma_f32_16x16x32_bf16(vf[nt][1], pf1, acc[nt], 0, 0, 0);
        }
        if (!more) break;
#pragma unroll
        for (int st = 0; st < 4; ++st) {
          kf[st][0] = kn[st][0];
          kf[st][1] = kn[st][1];
        }
        k0 = k1;
      }
    }

    // ---- combine partials across the 8 waves
    __syncthreads();  // all k-loops done; sm.p reads finished
#pragma unroll
    for (int nt = 0; nt < 4; ++nt)
      *(f32x4*)(&sm.red.acc[wave][lane][nt * 4]) = acc[nt];
    if (lg == 0) {
      sm.red.ml[wave][lr][0] = m;
      sm.red.ml[wave][lr][1] = l;
    }
    __syncthreads();

    if (wave < 4) {  // wave v -> h-block v; lane: q=lr, h=v*16+lg*4+r
      float mw[8];
#pragma unroll
      for (int w2 = 0; w2 < 8; ++w2) mw[w2] = sm.red.ml[w2][lr][0];
      float M = fmaxf(fmaxf(fmaxf(mw[0], mw[1]), fmaxf(mw[2], mw[3])),
                      fmaxf(fmaxf(mw[4], mw[5]), fmaxf(mw[6], mw[7])));
      float L = 0.f;
      f32x4 o = f32x4{0.f, 0.f, 0.f, 0.f};
#pragma unroll
      for (int w2 = 0; w2 < 8; ++w2) {
        const float e = __builtin_amdgcn_exp2f(mw[w2] - M);
        L += e * sm.red.ml[w2][lr][1];
        const f32x4 a = *(const f32x4*)(&sm.red.acc[w2][lane][wave * 4]);
        o[0] += e * a[0]; o[1] += e * a[1];
        o[2] += e * a[2]; o[3] += e * a[3];
      }
      const float invL = 1.0f / L;
      f32x4 res;
      res[0] = o[0] * invL; res[1] = o[1] * invL;
      res[2] = o[2] * invL; res[3] = o[3] * invL;
      *(f32x4*)(&out[(size_t)(b * T + q0 + lr) * H + wave * 16 + lg * 4]) = res;
    }
    __syncthreads();  // protect sm.red from next phase's sm.p writes
  }
}

// ---------------------------------------------------------------------------
extern "C" void kernel_launch(void* const* d_in, const int* in_sizes, int n_in,
                              void* d_out, int out_size, void* d_ws,
                              size_t ws_size, hipStream_t stream) {
  const float* x = (const float*)d_in[0];
  const float* Wk = (const float*)d_in[1];
  const float* Wq = (const float*)d_in[2];
  const float* Wv = (const float*)d_in[3];
  float* out = (float*)d_out;
  char* ws = (char*)d_ws;
  const size_t SZ = (size_t)B * T * H * sizeof(bf16_t);  // 2 MB each
  bf16_t* qb = (bf16_t*)ws;
  bf16_t* kb = (bf16_t*)(ws + SZ);
  bf16_t* vT = (bf16_t*)(ws + 2 * SZ);
  bf16_t* WT = (bf16_t*)(ws + 3 * SZ);  // 384 KB

  wconv_kernel<<<(3 * H * C + 255) / 256, 256, 0, stream>>>(Wk, Wq, Wv, WT);
  proj_kernel<<<(B * T) / 32, 256, 0, stream>>>(x, WT, qb, kb, vT);
  flash_kernel<<<dim3(B * T / 32), 512, 0, stream>>>(qb, kb, vT, out);
}